// Round 12
// baseline (1126.530 us; speedup 1.0000x reference)
//
#include <hip/hip_runtime.h>
#include <math.h>

#define NN 768
#define CSn 384
#define CZn 128
#define Hn 12
#define CONCATn 2112
#define LGS 772   // LDS attention row stride: %4==0 (float4 ok), %32==4 (bank shift/h)

// ---------------------------------------------------------------------------
// K1: linG[768][1152] = s @ [Wq|Wkv|Wqp|Wkvp] + bias.  Grid (48 rt, 18 ct).
// ---------------------------------------------------------------------------
__global__ __launch_bounds__(256, 4) void proj_gemm(
    const float* __restrict__ s,
    const float* __restrict__ Wq, const float* __restrict__ bq,
    const float* __restrict__ Wkv, const float* __restrict__ bkv,
    const float* __restrict__ Wqp, const float* __restrict__ bqp,
    const float* __restrict__ Wkvp, const float* __restrict__ bkvp,
    float* __restrict__ linG)
{
    const int rt = blockIdx.x;
    const int ct = blockIdx.y;
    const int t = threadIdx.x;
    const int r0 = rt * 16;
    __shared__ float sl[16 * 388];
    for (int x4 = t; x4 < 1536; x4 += 256) {
        const int r = x4 / 96, c4 = x4 % 96;
        *(float4*)&sl[r * 388 + c4 * 4] = *(const float4*)(s + (size_t)(r0 + r) * CSn + c4 * 4);
    }
    __syncthreads();
    const int c = t & 63, rq = t >> 6;
    const int col = ct * 64 + c;
    const float* Wp; int fout; float bias;
    if (col < 192)      { Wp = Wq + col;         fout = 192; bias = bq[col]; }
    else if (col < 576) { Wp = Wkv + (col-192);  fout = 384; bias = bkv[col-192]; }
    else if (col < 720) { Wp = Wqp + (col-576);  fout = 144; bias = bqp[col-576]; }
    else                { Wp = Wkvp + (col-720); fout = 432; bias = bkvp[col-720]; }
    float a0=bias, a1=bias, a2=bias, a3=bias;
    const float* s0 = sl + (rq*4+0)*388;
    const float* s1 = sl + (rq*4+1)*388;
    const float* s2 = sl + (rq*4+2)*388;
    const float* s3 = sl + (rq*4+3)*388;
    #pragma unroll 4
    for (int kk = 0; kk < 384; ++kk) {
        const float wv = *Wp; Wp += fout;
        a0 += s0[kk]*wv; a1 += s1[kk]*wv; a2 += s2[kk]*wv; a3 += s3[kk]*wv;
    }
    float* lr = linG + (size_t)(r0 + rq*4) * 1152 + col;
    lr[0] = a0; lr[1152] = a1; lr[2*1152] = a2; lr[3*1152] = a3;
}

// ---------------------------------------------------------------------------
// K2: scatter linG -> q [N][192], kT [192][768], v [N][192], qp [N][144],
//     kpT [144][768], vp [N][288]; block 0 builds WbT[12][128].
// ---------------------------------------------------------------------------
__global__ __launch_bounds__(256) void scatter_kernel(
    const float* __restrict__ linG, const float* __restrict__ rot, const float* __restrict__ trans,
    const float* __restrict__ Wb,
    float* __restrict__ q, float* __restrict__ kT, float* __restrict__ v,
    float* __restrict__ qp, float* __restrict__ kpT, float* __restrict__ vp,
    float* __restrict__ WbT)
{
    const int i = blockIdx.x, t = threadIdx.x;
    const float* lr = linG + (size_t)i * 1152;
    if (t < 192) q[(size_t)i*192 + t] = lr[t];
    for (int tt = t; tt < 384; tt += 256) {
        const int h = tt >> 5, cc = tt & 31;
        const float val = lr[192 + tt];
        if (cc < 16) kT[(size_t)(h*16 + cc)*NN + i] = val;
        else         v[(size_t)i*192 + h*16 + (cc-16)] = val;
    }
    const float R0 = rot[i*9+0], R1 = rot[i*9+1], R2 = rot[i*9+2];
    const float R3 = rot[i*9+3], R4 = rot[i*9+4], R5 = rot[i*9+5];
    const float R6 = rot[i*9+6], R7 = rot[i*9+7], R8 = rot[i*9+8];
    const float T0 = trans[i*3+0], T1 = trans[i*3+1], T2 = trans[i*3+2];
    if (t < 48) {
        const float px = lr[576 + t], py = lr[576 + 48 + t], pz = lr[576 + 96 + t];
        float* d = qp + (size_t)i*144 + t*3;
        d[0] = R0*px + R1*py + R2*pz + T0;
        d[1] = R3*px + R4*py + R5*pz + T1;
        d[2] = R6*px + R7*py + R8*pz + T2;
    }
    if (t < 144) {
        const float px = lr[720 + t], py = lr[720 + 144 + t], pz = lr[720 + 288 + t];
        const float gx = R0*px + R1*py + R2*pz + T0;
        const float gy = R3*px + R4*py + R5*pz + T1;
        const float gz = R6*px + R7*py + R8*pz + T2;
        const int h = t / 12, pp = t % 12;
        if (pp < 4) {
            float* d = kpT + (size_t)(h*12 + pp*3)*NN + i;
            d[0] = gx; d[NN] = gy; d[2*NN] = gz;
        } else {
            float* d = vp + (size_t)i*288 + ((h*8) + (pp-4))*3;
            d[0] = gx; d[1] = gy; d[2] = gz;
        }
    }
    if (i == 0) for (int x = t; x < 1536; x += 256) WbT[x] = Wb[(x & 127)*12 + (x >> 7)];
}

// ---------------------------------------------------------------------------
// K3: MEGA v2.  Grid (768 i).  Phases:
//  1a bias GEMV (quad-split z, LDS WbT) -> lg      [biasg fused in, bG deleted]
//  1b logits float4-j + softmax (in-place lg, same-thread RMW)
//  2  o / o_pt (coalesced scalar)   3 frame+norm   4 o_pair (float4 z, 2j/instr)
// ---------------------------------------------------------------------------
__global__ __launch_bounds__(256, 3) void mega_kernel(
    const float* __restrict__ mask,
    const float* __restrict__ q, const float* __restrict__ qp,
    const float* __restrict__ kT, const float* __restrict__ kpT,
    const float* __restrict__ WbT, const float* __restrict__ bb,
    const float* __restrict__ head_w,
    const float* __restrict__ z,
    const float* __restrict__ v, const float* __restrict__ vp,
    const float* __restrict__ rot, const float* __restrict__ trans,
    float* __restrict__ cat)
{
    const int i = blockIdx.x, t = threadIdx.x;
    const int w = t >> 6, l = t & 63;
    __shared__ float lg[Hn * LGS];   // 37056 B: bias, then attention (in-place)
    __shared__ float wbs[1536];      // 6144 B: WbT[12][128]; pts overlays after 1a
    __shared__ float qs[192], qps[144];
    float* pts = wbs;                // overlay (wbs dead after phase 1a)

    for (int x = t; x < 1536; x += 256) wbs[x] = WbT[x];
    if (t < 192) qs[t] = q[(size_t)i*192 + t];
    if (t < 144) qps[t] = qp[(size_t)i*144 + t];
    __syncthreads();
    const float mi = mask[i];
    const float S_QK = 0.14433756729740643f;   // sqrt(1/48)
    const float S_B  = 0.5773502691896258f;    // sqrt(1/3)
    const float S_PT = 0.1360827634879543f;    // sqrt(1/54)

    // ---- Phase 1a: bias = S_B*(z@Wb + bb) -> lg --------------------------
    {
        const int jl = t >> 2, g = t & 3;
        float bb3[3];
        #pragma unroll
        for (int hh = 0; hh < 3; ++hh) bb3[hh] = bb[3*g + hh];
        #pragma unroll 1
        for (int strip = 0; strip < 12; ++strip) {
            const int j = jl + strip*64;
            const float* zr = z + ((size_t)i * NN + j) * CZn + g * 4;
            float4 zv[8];
            #pragma unroll
            for (int u = 0; u < 8; ++u) zv[u] = *(const float4*)(zr + u * 16);  // 8 in flight
            float bh[12];
            #pragma unroll
            for (int h = 0; h < 12; ++h) bh[h] = 0.f;
            #pragma unroll
            for (int u = 0; u < 8; ++u) {
                const float* wb = wbs + u*16 + g*4;
                #pragma unroll
                for (int h = 0; h < 12; ++h) {
                    const float4 wv = *(const float4*)(wb + h * 128);
                    bh[h] += zv[u].x*wv.x + zv[u].y*wv.y + zv[u].z*wv.z + zv[u].w*wv.w;
                }
            }
            #pragma unroll
            for (int h = 0; h < 12; ++h) {
                bh[h] += __shfl_xor(bh[h], 1);
                bh[h] += __shfl_xor(bh[h], 2);
            }
            #pragma unroll
            for (int hh = 0; hh < 3; ++hh) {
                const float v01 = (g & 1) ? bh[3+hh] : bh[0+hh];
                const float v23 = (g & 1) ? bh[9+hh] : bh[6+hh];
                const float bsel = (g & 2) ? v23 : v01;
                lg[(3*g + hh)*LGS + j] = S_B * (bsel + bb3[hh]);
            }
        }
    }
    __syncthreads();

    // ---- Phase 1b: logits (float4 along j) + softmax, lg in-place --------
    #pragma unroll 1
    for (int hh = 0; hh < 3; ++hh) {
        const int h = w*3 + hh;    // wave-uniform
        float qreg[16], qpreg[12];
        #pragma unroll
        for (int c = 0; c < 16; ++c) qreg[c] = qs[h*16 + c];
        #pragma unroll
        for (int ee = 0; ee < 12; ++ee) qpreg[ee] = qps[h*12 + ee];
        const float coef = -0.5f * S_PT * log1pf(expf(head_w[h]));
        float e[12];
        #pragma unroll
        for (int strip = 0; strip < 3; ++strip) {
            const int j0 = strip*256 + 4*l;
            const float* kb  = kT  + (size_t)(h*16)*NN + j0;
            const float* kpb = kpT + (size_t)(h*12)*NN + j0;
            float qk0=0.f, qk1=0.f, qk2=0.f, qk3=0.f;
            #pragma unroll
            for (int c = 0; c < 16; ++c) {
                const float4 kv = *(const float4*)(kb + (size_t)c*NN);
                const float qc = qreg[c];
                qk0 += qc*kv.x; qk1 += qc*kv.y; qk2 += qc*kv.z; qk3 += qc*kv.w;
            }
            float d0=0.f, d1=0.f, d2=0.f, d3=0.f;
            #pragma unroll
            for (int ee = 0; ee < 12; ++ee) {
                const float4 kpv = *(const float4*)(kpb + (size_t)ee*NN);
                const float qe = qpreg[ee];
                const float u0 = qe-kpv.x, u1 = qe-kpv.y, u2 = qe-kpv.z, u3 = qe-kpv.w;
                d0 += u0*u0; d1 += u1*u1; d2 += u2*u2; d3 += u3*u3;
            }
            const float4 bias = *(const float4*)&lg[h*LGS + j0];
            const float4 mj = *(const float4*)(mask + j0);
            e[strip*4+0] = S_QK*qk0 + bias.x + coef*d0 + 100000.f*(mi*mj.x - 1.f);
            e[strip*4+1] = S_QK*qk1 + bias.y + coef*d1 + 100000.f*(mi*mj.y - 1.f);
            e[strip*4+2] = S_QK*qk2 + bias.z + coef*d2 + 100000.f*(mi*mj.z - 1.f);
            e[strip*4+3] = S_QK*qk3 + bias.w + coef*d3 + 100000.f*(mi*mj.w - 1.f);
        }
        float m = -1e30f;
        #pragma unroll
        for (int u = 0; u < 12; ++u) m = fmaxf(m, e[u]);
        #pragma unroll
        for (int off = 32; off > 0; off >>= 1) m = fmaxf(m, __shfl_xor(m, off));
        float ssum = 0.f;
        #pragma unroll
        for (int u = 0; u < 12; ++u) { e[u] = expf(e[u] - m); ssum += e[u]; }
        #pragma unroll
        for (int off = 32; off > 0; off >>= 1) ssum += __shfl_xor(ssum, off);
        const float inv = 1.0f / ssum;
        #pragma unroll
        for (int strip = 0; strip < 3; ++strip) {
            float4 av;
            av.x = e[strip*4+0]*inv; av.y = e[strip*4+1]*inv;
            av.z = e[strip*4+2]*inv; av.w = e[strip*4+3]*inv;
            *(float4*)&lg[h*LGS + strip*256 + 4*l] = av;   // same-thread RMW: safe
        }
    }
    __syncthreads();

    // ---- Phase 2: o (192) + o_pt (288), coalesced scalar src reads -------
    {
        float accA = 0.f;
        const float* srcA; int strA; int hA;
        if (t < 192) { srcA = v + t;          strA = 192; hA = t >> 4; }
        else         { srcA = vp + (t - 192); strA = 288; hA = (t - 192) / 24; }
        const float* arA = lg + hA * LGS;
        float accB = 0.f;
        const int cB = 64 + t;                 // vp cols 64..287 (t<224)
        const float* srcB = vp + cB;
        const float* arB = lg + (cB / 24) * LGS;
        const bool hasB = (t < 224);
        #pragma unroll 8
        for (int j = 0; j < NN; ++j) {
            accA += arA[j] * srcA[(size_t)j * strA];
            if (hasB) accB += arB[j] * srcB[(size_t)j * 288];
        }
        float* catr = cat + (size_t)i*CONCATn;
        if (t < 192) catr[t] = accA;
        else         pts[t - 192] = accA;
        if (hasB)    pts[64 + t] = accB;
    }
    __syncthreads();

    // ---- Phase 3: frame invert + norms -----------------------------------
    if (t < 96) {
        const float gx = pts[t*3+0] - trans[i*3+0];
        const float gy = pts[t*3+1] - trans[i*3+1];
        const float gz = pts[t*3+2] - trans[i*3+2];
        const float lx = rot[i*9+0]*gx + rot[i*9+3]*gy + rot[i*9+6]*gz;
        const float ly = rot[i*9+1]*gx + rot[i*9+4]*gy + rot[i*9+7]*gz;
        const float lz = rot[i*9+2]*gx + rot[i*9+5]*gy + rot[i*9+8]*gz;
        float* catr = cat + (size_t)i*CONCATn;
        catr[192 + t] = lx;
        catr[288 + t] = ly;
        catr[384 + t] = lz;
        catr[480 + t] = sqrtf(lx*lx + ly*ly + lz*lz + 1e-8f);
    }

    // ---- Phase 4: o_pair, float4 z + 2 j/wave-instr + shfl merge ---------
    {
        const int c4 = l & 31, jp = l >> 5;
        const float* zb = z + (size_t)i*NN*CZn + c4*4;
        const float* a0 = lg + (size_t)(3*w + 0)*LGS;
        const float* a1 = lg + (size_t)(3*w + 1)*LGS;
        const float* a2 = lg + (size_t)(3*w + 2)*LGS;
        float x00=0.f,x01=0.f,x02=0.f,x03=0.f;
        float x10=0.f,x11=0.f,x12=0.f,x13=0.f;
        float x20=0.f,x21=0.f,x22=0.f,x23=0.f;
        #pragma unroll 8
        for (int j2 = 0; j2 < 384; ++j2) {
            const int j = 2*j2 + jp;
            const float4 zv = *(const float4*)(zb + (size_t)j*CZn);
            const float A0 = a0[j], A1 = a1[j], A2 = a2[j];   // 2-way LDS broadcast
            x00 += A0*zv.x; x01 += A0*zv.y; x02 += A0*zv.z; x03 += A0*zv.w;
            x10 += A1*zv.x; x11 += A1*zv.y; x12 += A1*zv.z; x13 += A1*zv.w;
            x20 += A2*zv.x; x21 += A2*zv.y; x22 += A2*zv.z; x23 += A2*zv.w;
        }
        x00 += __shfl_xor(x00, 32); x01 += __shfl_xor(x01, 32);
        x02 += __shfl_xor(x02, 32); x03 += __shfl_xor(x03, 32);
        x10 += __shfl_xor(x10, 32); x11 += __shfl_xor(x11, 32);
        x12 += __shfl_xor(x12, 32); x13 += __shfl_xor(x13, 32);
        x20 += __shfl_xor(x20, 32); x21 += __shfl_xor(x21, 32);
        x22 += __shfl_xor(x22, 32); x23 += __shfl_xor(x23, 32);
        if (jp == 0) {
            float* cr = cat + (size_t)i*CONCATn + 576 + c4*4;
            float4 r0; r0.x=x00; r0.y=x01; r0.z=x02; r0.w=x03;
            float4 r1; r1.x=x10; r1.y=x11; r1.z=x12; r1.w=x13;
            float4 r2; r2.x=x20; r2.y=x21; r2.z=x22; r2.w=x23;
            *(float4*)(cr + (size_t)(3*w+0)*CZn) = r0;
            *(float4*)(cr + (size_t)(3*w+1)*CZn) = r1;
            *(float4*)(cr + (size_t)(3*w+2)*CZn) = r2;
        }
    }
}

// ---------------------------------------------------------------------------
// K4: out = cat @ Wout + bout.  Grid (192, 3), 128 thr.
// ---------------------------------------------------------------------------
__global__ __launch_bounds__(128) void out_kernel(
    const float* __restrict__ cat, const float* __restrict__ Wout,
    const float* __restrict__ bout, float* __restrict__ out)
{
    const int rt = blockIdx.x;
    const int ot = blockIdx.y;
    __shared__ float cl[4 * CONCATn];
    const int r0 = rt * 4;
    const float4* cb = (const float4*)(cat + (size_t)r0 * CONCATn);
    for (int idx = threadIdx.x; idx < CONCATn; idx += 128)
        ((float4*)cl)[idx] = cb[idx];
    __syncthreads();
    const int t = threadIdx.x;
    const int r  = t >> 5;
    const int o4 = t & 31;
    const int col = ot * 128 + o4 * 4;
    float4 acc; acc.x = 0.f; acc.y = 0.f; acc.z = 0.f; acc.w = 0.f;
    const float* wp = Wout + col;
    const float* cr = cl + r * CONCATn;
    #pragma unroll 8
    for (int kk = 0; kk < CONCATn; ++kk) {
        const float4 wv = *(const float4*)(wp + (size_t)kk * 384);
        const float cv = cr[kk];
        acc.x += cv * wv.x; acc.y += cv * wv.y;
        acc.z += cv * wv.z; acc.w += cv * wv.w;
    }
    const float4 bo = *(const float4*)(bout + col);
    acc.x += bo.x; acc.y += bo.y; acc.z += bo.z; acc.w += bo.w;
    *(float4*)(out + (size_t)(r0 + r) * 384 + col) = acc;
}

// ---------------------------------------------------------------------------
extern "C" void kernel_launch(void* const* d_in, const int* in_sizes, int n_in,
                              void* d_out, int out_size, void* d_ws, size_t ws_size,
                              hipStream_t stream)
{
    const float* s     = (const float*)d_in[0];
    const float* z     = (const float*)d_in[1];
    const float* rot   = (const float*)d_in[2];
    const float* trans = (const float*)d_in[3];
    const float* mask  = (const float*)d_in[4];
    const float* Wq    = (const float*)d_in[5];
    const float* bq    = (const float*)d_in[6];
    const float* Wkv   = (const float*)d_in[7];
    const float* bkv   = (const float*)d_in[8];
    const float* Wqp   = (const float*)d_in[9];
    const float* bqp   = (const float*)d_in[10];
    const float* Wkvp  = (const float*)d_in[11];
    const float* bkvp  = (const float*)d_in[12];
    const float* Wb    = (const float*)d_in[13];
    const float* bb    = (const float*)d_in[14];
    const float* head_w= (const float*)d_in[15];
    const float* Wout  = (const float*)d_in[16];
    const float* bout  = (const float*)d_in[17];
    float* out = (float*)d_out;

    float* ws    = (float*)d_ws;
    float* q     = ws;                  // 147456  [N][192]
    float* kT    = q     + 147456;      // 147456  [192][N]
    float* qp    = kT    + 147456;      // 110592  [N][144]
    float* kpT   = qp    + 110592;      // 110592  [144][N]
    float* v     = kpT   + 110592;      // 147456  [N][192]
    float* vp    = v     + 147456;      // 221184  [N][288]
    float* WbT   = vp    + 221184;      // 1536    [12][128]
    float* cat   = WbT   + 1536;        // 1622016
    float* linG  = cat   + 1622016;     // 884736  (768x1152)

    hipLaunchKernelGGL(proj_gemm, dim3(48, 18), dim3(256), 0, stream,
        s, Wq, bq, Wkv, bkv, Wqp, bqp, Wkvp, bkvp, linG);
    hipLaunchKernelGGL(scatter_kernel, dim3(768), dim3(256), 0, stream,
        linG, rot, trans, Wb, q, kT, v, qp, kpT, vp, WbT);
    hipLaunchKernelGGL(mega_kernel, dim3(768), dim3(256), 0, stream,
        mask, q, qp, kT, kpT, WbT, bb, head_w, z, v, vp, rot, trans, cat);
    hipLaunchKernelGGL(out_kernel, dim3(192, 3), dim3(128), 0, stream,
        cat, Wout, bout, out);
}

// Round 13
// 637.742 us; speedup vs baseline: 1.7664x; 1.7664x over previous
//
#include <hip/hip_runtime.h>
#include <math.h>

#define NN 768
#define CSn 384
#define CZn 128
#define Hn 12
#define CONCATn 2112
#define LGS 772   // LDS attention row stride: %4==0 (float4 ok), %32==4 (bank shift/h)

// ---------------------------------------------------------------------------
// K1: linG[768][1152] = s @ [Wq|Wkv|Wqp|Wkvp] + bias.  Grid (48 rt, 18 ct).
// ---------------------------------------------------------------------------
__global__ __launch_bounds__(256, 4) void proj_gemm(
    const float* __restrict__ s,
    const float* __restrict__ Wq, const float* __restrict__ bq,
    const float* __restrict__ Wkv, const float* __restrict__ bkv,
    const float* __restrict__ Wqp, const float* __restrict__ bqp,
    const float* __restrict__ Wkvp, const float* __restrict__ bkvp,
    float* __restrict__ linG)
{
    const int rt = blockIdx.x;
    const int ct = blockIdx.y;
    const int t = threadIdx.x;
    const int r0 = rt * 16;
    __shared__ float sl[16 * 388];
    for (int x4 = t; x4 < 1536; x4 += 256) {
        const int r = x4 / 96, c4 = x4 % 96;
        *(float4*)&sl[r * 388 + c4 * 4] = *(const float4*)(s + (size_t)(r0 + r) * CSn + c4 * 4);
    }
    __syncthreads();
    const int c = t & 63, rq = t >> 6;
    const int col = ct * 64 + c;
    const float* Wp; int fout; float bias;
    if (col < 192)      { Wp = Wq + col;         fout = 192; bias = bq[col]; }
    else if (col < 576) { Wp = Wkv + (col-192);  fout = 384; bias = bkv[col-192]; }
    else if (col < 720) { Wp = Wqp + (col-576);  fout = 144; bias = bqp[col-576]; }
    else                { Wp = Wkvp + (col-720); fout = 432; bias = bkvp[col-720]; }
    float a0=bias, a1=bias, a2=bias, a3=bias;
    const float* s0 = sl + (rq*4+0)*388;
    const float* s1 = sl + (rq*4+1)*388;
    const float* s2 = sl + (rq*4+2)*388;
    const float* s3 = sl + (rq*4+3)*388;
    #pragma unroll 4
    for (int kk = 0; kk < 384; ++kk) {
        const float wv = *Wp; Wp += fout;
        a0 += s0[kk]*wv; a1 += s1[kk]*wv; a2 += s2[kk]*wv; a3 += s3[kk]*wv;
    }
    float* lr = linG + (size_t)(r0 + rq*4) * 1152 + col;
    lr[0] = a0; lr[1152] = a1; lr[2*1152] = a2; lr[3*1152] = a3;
}

// ---------------------------------------------------------------------------
// K2: scatter linG -> q [N][192], kT [192][768], v [N][192], qp [N][144],
//     kpT [144][768], vp [N][288]; block 0 builds WbT[12][128].
// ---------------------------------------------------------------------------
__global__ __launch_bounds__(256) void scatter_kernel(
    const float* __restrict__ linG, const float* __restrict__ rot, const float* __restrict__ trans,
    const float* __restrict__ Wb,
    float* __restrict__ q, float* __restrict__ kT, float* __restrict__ v,
    float* __restrict__ qp, float* __restrict__ kpT, float* __restrict__ vp,
    float* __restrict__ WbT)
{
    const int i = blockIdx.x, t = threadIdx.x;
    const float* lr = linG + (size_t)i * 1152;
    if (t < 192) q[(size_t)i*192 + t] = lr[t];
    for (int tt = t; tt < 384; tt += 256) {
        const int h = tt >> 5, cc = tt & 31;
        const float val = lr[192 + tt];
        if (cc < 16) kT[(size_t)(h*16 + cc)*NN + i] = val;
        else         v[(size_t)i*192 + h*16 + (cc-16)] = val;
    }
    const float R0 = rot[i*9+0], R1 = rot[i*9+1], R2 = rot[i*9+2];
    const float R3 = rot[i*9+3], R4 = rot[i*9+4], R5 = rot[i*9+5];
    const float R6 = rot[i*9+6], R7 = rot[i*9+7], R8 = rot[i*9+8];
    const float T0 = trans[i*3+0], T1 = trans[i*3+1], T2 = trans[i*3+2];
    if (t < 48) {
        const float px = lr[576 + t], py = lr[576 + 48 + t], pz = lr[576 + 96 + t];
        float* d = qp + (size_t)i*144 + t*3;
        d[0] = R0*px + R1*py + R2*pz + T0;
        d[1] = R3*px + R4*py + R5*pz + T1;
        d[2] = R6*px + R7*py + R8*pz + T2;
    }
    if (t < 144) {
        const float px = lr[720 + t], py = lr[720 + 144 + t], pz = lr[720 + 288 + t];
        const float gx = R0*px + R1*py + R2*pz + T0;
        const float gy = R3*px + R4*py + R5*pz + T1;
        const float gz = R6*px + R7*py + R8*pz + T2;
        const int h = t / 12, pp = t % 12;
        if (pp < 4) {
            float* d = kpT + (size_t)(h*12 + pp*3)*NN + i;
            d[0] = gx; d[NN] = gy; d[2*NN] = gz;
        } else {
            float* d = vp + (size_t)i*288 + ((h*8) + (pp-4))*3;
            d[0] = gx; d[1] = gy; d[2] = gz;
        }
    }
    if (i == 0) for (int x = t; x < 1536; x += 256) WbT[x] = Wb[(x & 127)*12 + (x >> 7)];
}

// ---------------------------------------------------------------------------
// K3: biasg = S_B*(z@Wb + bb) -> bG[i][h][j].  Grid (12 jt, 768 i).
// SEPARATE kernel (r12 lesson: fusing this z-stream into mega thrashes L2 and
// amplifies shared-operand traffic 9x).  8 up-front z loads + LDS WbT.
// ---------------------------------------------------------------------------
__global__ __launch_bounds__(256, 4) void biasg_kernel(
    const float* __restrict__ z, const float* __restrict__ WbT,
    const float* __restrict__ bb, float* __restrict__ bG)
{
    const int jt = blockIdx.x, i = blockIdx.y, t = threadIdx.x;
    __shared__ float wbs[1536];   // 6 KB: WbT[12][128]
    for (int x = t; x < 1536; x += 256) wbs[x] = WbT[x];
    __syncthreads();

    const int jl = t >> 2, g = t & 3;
    const int j = jt * 64 + jl;
    const float* zr = z + ((size_t)i * NN + j) * CZn + g * 4;
    float4 zv[8];
    #pragma unroll
    for (int u = 0; u < 8; ++u) zv[u] = *(const float4*)(zr + u * 16);   // 8 in flight

    float bh[12];
    #pragma unroll
    for (int h = 0; h < 12; ++h) bh[h] = 0.f;
    #pragma unroll
    for (int u = 0; u < 8; ++u) {
        const float* wb = wbs + u*16 + g*4;
        #pragma unroll
        for (int h = 0; h < 12; ++h) {
            const float4 wv = *(const float4*)(wb + h * 128);   // LDS b128 broadcast
            bh[h] += zv[u].x*wv.x + zv[u].y*wv.y + zv[u].z*wv.z + zv[u].w*wv.w;
        }
    }
    #pragma unroll
    for (int h = 0; h < 12; ++h) {
        bh[h] += __shfl_xor(bh[h], 1);
        bh[h] += __shfl_xor(bh[h], 2);
    }
    float bsel[3];
    #pragma unroll
    for (int hh = 0; hh < 3; ++hh) {
        const float v01 = (g & 1) ? bh[3+hh] : bh[0+hh];
        const float v23 = (g & 1) ? bh[9+hh] : bh[6+hh];
        bsel[hh] = (g & 2) ? v23 : v01;
    }
    float* bgr = bG + (size_t)i * (Hn*NN) + j;
    #pragma unroll
    for (int hh = 0; hh < 3; ++hh) {
        const int h = 3*g + hh;
        bgr[(size_t)h * NN] = 0.5773502691896258f * (bsel[hh] + bb[h]);
    }
}

// ---------------------------------------------------------------------------
// K4: MEGA v3.  Grid (768 i).  Phases:
//  1 logits (float4-j, bias from bG) + softmax -> lg (LDS)
//  2 o / o_pt (coalesced scalar)   3 frame+norm   4 o_pair (float4 z, shfl)
// ---------------------------------------------------------------------------
__global__ __launch_bounds__(256, 3) void mega_kernel(
    const float* __restrict__ mask,
    const float* __restrict__ q, const float* __restrict__ qp,
    const float* __restrict__ kT, const float* __restrict__ kpT,
    const float* __restrict__ bG, const float* __restrict__ head_w,
    const float* __restrict__ z,
    const float* __restrict__ v, const float* __restrict__ vp,
    const float* __restrict__ rot, const float* __restrict__ trans,
    float* __restrict__ cat)
{
    const int i = blockIdx.x, t = threadIdx.x;
    const int w = t >> 6, l = t & 63;
    __shared__ float lg[Hn * LGS];   // 37056 B attention
    __shared__ float qs[192], qps[144], pts[288];
    if (t < 192) qs[t] = q[(size_t)i*192 + t];
    if (t < 144) qps[t] = qp[(size_t)i*144 + t];
    __syncthreads();
    const float mi = mask[i];
    const float S_QK = 0.14433756729740643f;   // sqrt(1/48)
    const float S_PT = 0.1360827634879543f;    // sqrt(1/54)

    // ---- Phase 1: logits (float4 along j, bias from bG) + softmax --------
    #pragma unroll 1
    for (int hh = 0; hh < 3; ++hh) {
        const int h = w*3 + hh;    // wave-uniform
        float qreg[16], qpreg[12];
        #pragma unroll
        for (int c = 0; c < 16; ++c) qreg[c] = qs[h*16 + c];
        #pragma unroll
        for (int ee = 0; ee < 12; ++ee) qpreg[ee] = qps[h*12 + ee];
        const float coef = -0.5f * S_PT * log1pf(expf(head_w[h]));
        float e[12];
        #pragma unroll
        for (int strip = 0; strip < 3; ++strip) {
            const int j0 = strip*256 + 4*l;
            const float* kb  = kT  + (size_t)(h*16)*NN + j0;
            const float* kpb = kpT + (size_t)(h*12)*NN + j0;
            float qk0=0.f, qk1=0.f, qk2=0.f, qk3=0.f;
            #pragma unroll
            for (int c = 0; c < 16; ++c) {
                const float4 kv = *(const float4*)(kb + (size_t)c*NN);
                const float qc = qreg[c];
                qk0 += qc*kv.x; qk1 += qc*kv.y; qk2 += qc*kv.z; qk3 += qc*kv.w;
            }
            float d0=0.f, d1=0.f, d2=0.f, d3=0.f;
            #pragma unroll
            for (int ee = 0; ee < 12; ++ee) {
                const float4 kpv = *(const float4*)(kpb + (size_t)ee*NN);
                const float qe = qpreg[ee];
                const float u0 = qe-kpv.x, u1 = qe-kpv.y, u2 = qe-kpv.z, u3 = qe-kpv.w;
                d0 += u0*u0; d1 += u1*u1; d2 += u2*u2; d3 += u3*u3;
            }
            const float4 bias = *(const float4*)(bG + (size_t)i*(Hn*NN) + (size_t)h*NN + j0);
            const float4 mj = *(const float4*)(mask + j0);
            e[strip*4+0] = S_QK*qk0 + bias.x + coef*d0 + 100000.f*(mi*mj.x - 1.f);
            e[strip*4+1] = S_QK*qk1 + bias.y + coef*d1 + 100000.f*(mi*mj.y - 1.f);
            e[strip*4+2] = S_QK*qk2 + bias.z + coef*d2 + 100000.f*(mi*mj.z - 1.f);
            e[strip*4+3] = S_QK*qk3 + bias.w + coef*d3 + 100000.f*(mi*mj.w - 1.f);
        }
        float m = -1e30f;
        #pragma unroll
        for (int u = 0; u < 12; ++u) m = fmaxf(m, e[u]);
        #pragma unroll
        for (int off = 32; off > 0; off >>= 1) m = fmaxf(m, __shfl_xor(m, off));
        float ssum = 0.f;
        #pragma unroll
        for (int u = 0; u < 12; ++u) { e[u] = expf(e[u] - m); ssum += e[u]; }
        #pragma unroll
        for (int off = 32; off > 0; off >>= 1) ssum += __shfl_xor(ssum, off);
        const float inv = 1.0f / ssum;
        #pragma unroll
        for (int strip = 0; strip < 3; ++strip) {
            float4 av;
            av.x = e[strip*4+0]*inv; av.y = e[strip*4+1]*inv;
            av.z = e[strip*4+2]*inv; av.w = e[strip*4+3]*inv;
            *(float4*)&lg[h*LGS + strip*256 + 4*l] = av;
        }
    }
    __syncthreads();

    // ---- Phase 2: o (192) + o_pt (288), coalesced scalar src reads -------
    {
        float accA = 0.f;
        const float* srcA; int strA; int hA;
        if (t < 192) { srcA = v + t;          strA = 192; hA = t >> 4; }
        else         { srcA = vp + (t - 192); strA = 288; hA = (t - 192) / 24; }
        const float* arA = lg + hA * LGS;
        float accB = 0.f;
        const int cB = 64 + t;                 // vp cols 64..287 (t<224)
        const float* srcB = vp + cB;
        const float* arB = lg + (cB / 24) * LGS;
        const bool hasB = (t < 224);
        #pragma unroll 8
        for (int j = 0; j < NN; ++j) {
            accA += arA[j] * srcA[(size_t)j * strA];
            if (hasB) accB += arB[j] * srcB[(size_t)j * 288];
        }
        float* catr = cat + (size_t)i*CONCATn;
        if (t < 192) catr[t] = accA;
        else         pts[t - 192] = accA;
        if (hasB)    pts[64 + t] = accB;
    }
    __syncthreads();

    // ---- Phase 3: frame invert + norms -----------------------------------
    if (t < 96) {
        const float gx = pts[t*3+0] - trans[i*3+0];
        const float gy = pts[t*3+1] - trans[i*3+1];
        const float gz = pts[t*3+2] - trans[i*3+2];
        const float lx = rot[i*9+0]*gx + rot[i*9+3]*gy + rot[i*9+6]*gz;
        const float ly = rot[i*9+1]*gx + rot[i*9+4]*gy + rot[i*9+7]*gz;
        const float lz = rot[i*9+2]*gx + rot[i*9+5]*gy + rot[i*9+8]*gz;
        float* catr = cat + (size_t)i*CONCATn;
        catr[192 + t] = lx;
        catr[288 + t] = ly;
        catr[384 + t] = lz;
        catr[480 + t] = sqrtf(lx*lx + ly*ly + lz*lz + 1e-8f);
    }

    // ---- Phase 4: o_pair, float4 z + 2 j/wave-instr + shfl merge ---------
    {
        const int c4 = l & 31, jp = l >> 5;
        const float* zb = z + (size_t)i*NN*CZn + c4*4;
        const float* a0 = lg + (size_t)(3*w + 0)*LGS;
        const float* a1 = lg + (size_t)(3*w + 1)*LGS;
        const float* a2 = lg + (size_t)(3*w + 2)*LGS;
        float x00=0.f,x01=0.f,x02=0.f,x03=0.f;
        float x10=0.f,x11=0.f,x12=0.f,x13=0.f;
        float x20=0.f,x21=0.f,x22=0.f,x23=0.f;
        #pragma unroll 8
        for (int j2 = 0; j2 < 384; ++j2) {
            const int j = 2*j2 + jp;
            const float4 zv = *(const float4*)(zb + (size_t)j*CZn);
            const float A0 = a0[j], A1 = a1[j], A2 = a2[j];   // 2-way LDS broadcast
            x00 += A0*zv.x; x01 += A0*zv.y; x02 += A0*zv.z; x03 += A0*zv.w;
            x10 += A1*zv.x; x11 += A1*zv.y; x12 += A1*zv.z; x13 += A1*zv.w;
            x20 += A2*zv.x; x21 += A2*zv.y; x22 += A2*zv.z; x23 += A2*zv.w;
        }
        x00 += __shfl_xor(x00, 32); x01 += __shfl_xor(x01, 32);
        x02 += __shfl_xor(x02, 32); x03 += __shfl_xor(x03, 32);
        x10 += __shfl_xor(x10, 32); x11 += __shfl_xor(x11, 32);
        x12 += __shfl_xor(x12, 32); x13 += __shfl_xor(x13, 32);
        x20 += __shfl_xor(x20, 32); x21 += __shfl_xor(x21, 32);
        x22 += __shfl_xor(x22, 32); x23 += __shfl_xor(x23, 32);
        if (jp == 0) {
            float* cr = cat + (size_t)i*CONCATn + 576 + c4*4;
            float4 r0; r0.x=x00; r0.y=x01; r0.z=x02; r0.w=x03;
            float4 r1; r1.x=x10; r1.y=x11; r1.z=x12; r1.w=x13;
            float4 r2; r2.x=x20; r2.y=x21; r2.z=x22; r2.w=x23;
            *(float4*)(cr + (size_t)(3*w+0)*CZn) = r0;
            *(float4*)(cr + (size_t)(3*w+1)*CZn) = r1;
            *(float4*)(cr + (size_t)(3*w+2)*CZn) = r2;
        }
    }
}

// ---------------------------------------------------------------------------
// K5: out = cat @ Wout + bout.  Grid (192, 3), 128 thr.
// ---------------------------------------------------------------------------
__global__ __launch_bounds__(128) void out_kernel(
    const float* __restrict__ cat, const float* __restrict__ Wout,
    const float* __restrict__ bout, float* __restrict__ out)
{
    const int rt = blockIdx.x;
    const int ot = blockIdx.y;
    __shared__ float cl[4 * CONCATn];
    const int r0 = rt * 4;
    const float4* cb = (const float4*)(cat + (size_t)r0 * CONCATn);
    for (int idx = threadIdx.x; idx < CONCATn; idx += 128)
        ((float4*)cl)[idx] = cb[idx];
    __syncthreads();
    const int t = threadIdx.x;
    const int r  = t >> 5;
    const int o4 = t & 31;
    const int col = ot * 128 + o4 * 4;
    float4 acc; acc.x = 0.f; acc.y = 0.f; acc.z = 0.f; acc.w = 0.f;
    const float* wp = Wout + col;
    const float* cr = cl + r * CONCATn;
    #pragma unroll 8
    for (int kk = 0; kk < CONCATn; ++kk) {
        const float4 wv = *(const float4*)(wp + (size_t)kk * 384);
        const float cv = cr[kk];
        acc.x += cv * wv.x; acc.y += cv * wv.y;
        acc.z += cv * wv.z; acc.w += cv * wv.w;
    }
    const float4 bo = *(const float4*)(bout + col);
    acc.x += bo.x; acc.y += bo.y; acc.z += bo.z; acc.w += bo.w;
    *(float4*)(out + (size_t)(r0 + r) * 384 + col) = acc;
}

// ---------------------------------------------------------------------------
extern "C" void kernel_launch(void* const* d_in, const int* in_sizes, int n_in,
                              void* d_out, int out_size, void* d_ws, size_t ws_size,
                              hipStream_t stream)
{
    const float* s     = (const float*)d_in[0];
    const float* z     = (const float*)d_in[1];
    const float* rot   = (const float*)d_in[2];
    const float* trans = (const float*)d_in[3];
    const float* mask  = (const float*)d_in[4];
    const float* Wq    = (const float*)d_in[5];
    const float* bq    = (const float*)d_in[6];
    const float* Wkv   = (const float*)d_in[7];
    const float* bkv   = (const float*)d_in[8];
    const float* Wqp   = (const float*)d_in[9];
    const float* bqp   = (const float*)d_in[10];
    const float* Wkvp  = (const float*)d_in[11];
    const float* bkvp  = (const float*)d_in[12];
    const float* Wb    = (const float*)d_in[13];
    const float* bb    = (const float*)d_in[14];
    const float* head_w= (const float*)d_in[15];
    const float* Wout  = (const float*)d_in[16];
    const float* bout  = (const float*)d_in[17];
    float* out = (float*)d_out;

    float* ws    = (float*)d_ws;
    float* q     = ws;                  // 147456  [N][192]
    float* kT    = q     + 147456;      // 147456  [192][N]
    float* qp    = kT    + 147456;      // 110592  [N][144]
    float* kpT   = qp    + 110592;      // 110592  [144][N]
    float* v     = kpT   + 110592;      // 147456  [N][192]
    float* vp    = v     + 147456;      // 221184  [N][288]
    float* WbT   = vp    + 221184;      // 1536    [12][128]
    float* cat   = WbT   + 1536;        // 1622016
    float* bG    = cat   + 1622016;     // 7077888 (28 MB; overlaid with linG)
    float* linG  = bG;                  // dead before biasg runs

    hipLaunchKernelGGL(proj_gemm, dim3(48, 18), dim3(256), 0, stream,
        s, Wq, bq, Wkv, bkv, Wqp, bqp, Wkvp, bkvp, linG);
    hipLaunchKernelGGL(scatter_kernel, dim3(768), dim3(256), 0, stream,
        linG, rot, trans, Wb, q, kT, v, qp, kpT, vp, WbT);
    hipLaunchKernelGGL(biasg_kernel, dim3(12, 768), dim3(256), 0, stream,
        z, WbT, bb, bG);
    hipLaunchKernelGGL(mega_kernel, dim3(768), dim3(256), 0, stream,
        mask, q, qp, kT, kpT, bG, head_w, z, v, vp, rot, trans, cat);
    hipLaunchKernelGGL(out_kernel, dim3(192, 3), dim3(128), 0, stream,
        cat, Wout, bout, out);
}

// Round 14
// 498.031 us; speedup vs baseline: 2.2620x; 1.2805x over previous
//
#include <hip/hip_runtime.h>
#include <math.h>

#define NN 768
#define CSn 384
#define CZn 128
#define Hn 12
#define CONCATn 2112
#define LGS 772   // LDS attention row stride: %4==0 (float4 ok), %32==4 (bank shift/h)

// ---------------------------------------------------------------------------
// K1: linG[768][1152] = s @ [Wq|Wkv|Wqp|Wkvp] + bias.  Grid (48 rt, 18 ct).
// ---------------------------------------------------------------------------
__global__ __launch_bounds__(256, 4) void proj_gemm(
    const float* __restrict__ s,
    const float* __restrict__ Wq, const float* __restrict__ bq,
    const float* __restrict__ Wkv, const float* __restrict__ bkv,
    const float* __restrict__ Wqp, const float* __restrict__ bqp,
    const float* __restrict__ Wkvp, const float* __restrict__ bkvp,
    float* __restrict__ linG)
{
    const int rt = blockIdx.x;
    const int ct = blockIdx.y;
    const int t = threadIdx.x;
    const int r0 = rt * 16;
    __shared__ float sl[16 * 388];
    for (int x4 = t; x4 < 1536; x4 += 256) {
        const int r = x4 / 96, c4 = x4 % 96;
        *(float4*)&sl[r * 388 + c4 * 4] = *(const float4*)(s + (size_t)(r0 + r) * CSn + c4 * 4);
    }
    __syncthreads();
    const int c = t & 63, rq = t >> 6;
    const int col = ct * 64 + c;
    const float* Wp; int fout; float bias;
    if (col < 192)      { Wp = Wq + col;         fout = 192; bias = bq[col]; }
    else if (col < 576) { Wp = Wkv + (col-192);  fout = 384; bias = bkv[col-192]; }
    else if (col < 720) { Wp = Wqp + (col-576);  fout = 144; bias = bqp[col-576]; }
    else                { Wp = Wkvp + (col-720); fout = 432; bias = bkvp[col-720]; }
    float a0=bias, a1=bias, a2=bias, a3=bias;
    const float* s0 = sl + (rq*4+0)*388;
    const float* s1 = sl + (rq*4+1)*388;
    const float* s2 = sl + (rq*4+2)*388;
    const float* s3 = sl + (rq*4+3)*388;
    #pragma unroll 4
    for (int kk = 0; kk < 384; ++kk) {
        const float wv = *Wp; Wp += fout;
        a0 += s0[kk]*wv; a1 += s1[kk]*wv; a2 += s2[kk]*wv; a3 += s3[kk]*wv;
    }
    float* lr = linG + (size_t)(r0 + rq*4) * 1152 + col;
    lr[0] = a0; lr[1152] = a1; lr[2*1152] = a2; lr[3*1152] = a3;
}

// ---------------------------------------------------------------------------
// K2: scatter linG -> q [N][192], kT [192][768], v [N][192], qp [N][144],
//     kpT [144][768], vp [N][288]; block 0 builds WbT[12][128].
// ---------------------------------------------------------------------------
__global__ __launch_bounds__(256) void scatter_kernel(
    const float* __restrict__ linG, const float* __restrict__ rot, const float* __restrict__ trans,
    const float* __restrict__ Wb,
    float* __restrict__ q, float* __restrict__ kT, float* __restrict__ v,
    float* __restrict__ qp, float* __restrict__ kpT, float* __restrict__ vp,
    float* __restrict__ WbT)
{
    const int i = blockIdx.x, t = threadIdx.x;
    const float* lr = linG + (size_t)i * 1152;
    if (t < 192) q[(size_t)i*192 + t] = lr[t];
    for (int tt = t; tt < 384; tt += 256) {
        const int h = tt >> 5, cc = tt & 31;
        const float val = lr[192 + tt];
        if (cc < 16) kT[(size_t)(h*16 + cc)*NN + i] = val;
        else         v[(size_t)i*192 + h*16 + (cc-16)] = val;
    }
    const float R0 = rot[i*9+0], R1 = rot[i*9+1], R2 = rot[i*9+2];
    const float R3 = rot[i*9+3], R4 = rot[i*9+4], R5 = rot[i*9+5];
    const float R6 = rot[i*9+6], R7 = rot[i*9+7], R8 = rot[i*9+8];
    const float T0 = trans[i*3+0], T1 = trans[i*3+1], T2 = trans[i*3+2];
    if (t < 48) {
        const float px = lr[576 + t], py = lr[576 + 48 + t], pz = lr[576 + 96 + t];
        float* d = qp + (size_t)i*144 + t*3;
        d[0] = R0*px + R1*py + R2*pz + T0;
        d[1] = R3*px + R4*py + R5*pz + T1;
        d[2] = R6*px + R7*py + R8*pz + T2;
    }
    if (t < 144) {
        const float px = lr[720 + t], py = lr[720 + 144 + t], pz = lr[720 + 288 + t];
        const float gx = R0*px + R1*py + R2*pz + T0;
        const float gy = R3*px + R4*py + R5*pz + T1;
        const float gz = R6*px + R7*py + R8*pz + T2;
        const int h = t / 12, pp = t % 12;
        if (pp < 4) {
            float* d = kpT + (size_t)(h*12 + pp*3)*NN + i;
            d[0] = gx; d[NN] = gy; d[2*NN] = gz;
        } else {
            float* d = vp + (size_t)i*288 + ((h*8) + (pp-4))*3;
            d[0] = gx; d[1] = gy; d[2] = gz;
        }
    }
    if (i == 0) for (int x = t; x < 1536; x += 256) WbT[x] = Wb[(x & 127)*12 + (x >> 7)];
}

// ---------------------------------------------------------------------------
// K3: biasg = S_B*(z@Wb + bb) -> bG[i][h][j].  Grid (12 jt, 768 i).
// Separate kernel (r12 lesson: fusing the z-stream into mega thrashes L2).
// ---------------------------------------------------------------------------
__global__ __launch_bounds__(256, 4) void biasg_kernel(
    const float* __restrict__ z, const float* __restrict__ WbT,
    const float* __restrict__ bb, float* __restrict__ bG)
{
    const int jt = blockIdx.x, i = blockIdx.y, t = threadIdx.x;
    __shared__ float wbs[1536];   // 6 KB: WbT[12][128]
    for (int x = t; x < 1536; x += 256) wbs[x] = WbT[x];
    __syncthreads();

    const int jl = t >> 2, g = t & 3;
    const int j = jt * 64 + jl;
    const float* zr = z + ((size_t)i * NN + j) * CZn + g * 4;
    float4 zv[8];
    #pragma unroll
    for (int u = 0; u < 8; ++u) zv[u] = *(const float4*)(zr + u * 16);   // 8 in flight

    float bh[12];
    #pragma unroll
    for (int h = 0; h < 12; ++h) bh[h] = 0.f;
    #pragma unroll
    for (int u = 0; u < 8; ++u) {
        const float* wb = wbs + u*16 + g*4;
        #pragma unroll
        for (int h = 0; h < 12; ++h) {
            const float4 wv = *(const float4*)(wb + h * 128);   // LDS b128 broadcast
            bh[h] += zv[u].x*wv.x + zv[u].y*wv.y + zv[u].z*wv.z + zv[u].w*wv.w;
        }
    }
    #pragma unroll
    for (int h = 0; h < 12; ++h) {
        bh[h] += __shfl_xor(bh[h], 1);
        bh[h] += __shfl_xor(bh[h], 2);
    }
    float bsel[3];
    #pragma unroll
    for (int hh = 0; hh < 3; ++hh) {
        const float v01 = (g & 1) ? bh[3+hh] : bh[0+hh];
        const float v23 = (g & 1) ? bh[9+hh] : bh[6+hh];
        bsel[hh] = (g & 2) ? v23 : v01;
    }
    float* bgr = bG + (size_t)i * (Hn*NN) + j;
    #pragma unroll
    for (int hh = 0; hh < 3; ++hh) {
        const int h = 3*g + hh;
        bgr[(size_t)h * NN] = 0.5773502691896258f * (bsel[hh] + bb[h]);
    }
}

// ---------------------------------------------------------------------------
// K4: MEGA — ABLATION build: phases 1-3 EXACTLY as round 11 (scalar logits,
// measured 295 us); ONLY phase 4 is the float4+shfl o_pair from round 13.
// ---------------------------------------------------------------------------
__global__ __launch_bounds__(256, 3) void mega_kernel(
    const float* __restrict__ mask,
    const float* __restrict__ q, const float* __restrict__ qp,
    const float* __restrict__ kT, const float* __restrict__ kpT,
    const float* __restrict__ bG, const float* __restrict__ head_w,
    const float* __restrict__ z,
    const float* __restrict__ v, const float* __restrict__ vp,
    const float* __restrict__ rot, const float* __restrict__ trans,
    float* __restrict__ cat)
{
    const int i = blockIdx.x, t = threadIdx.x;
    const int w = t >> 6, l = t & 63;
    __shared__ float lg[Hn * LGS];     // 37 KB attention
    __shared__ float qs[192], qps[144], coefS[12];
    __shared__ float pts[288];
    if (t < 192) qs[t] = q[(size_t)i*192 + t];
    if (t < 144) qps[t] = qp[(size_t)i*144 + t];
    if (t < 12) coefS[t] = -0.5f * 0.1360827634879543f * log1pf(expf(head_w[t]));
    __syncthreads();
    const float mi = mask[i];

    // ---- Phase 1 (r11 exact): scalar logits + softmax --------------------
    #pragma unroll 1
    for (int hh = 0; hh < 3; ++hh) {
        const int h = w*3 + hh;
        float qreg[16], qpreg[12];
        #pragma unroll
        for (int c = 0; c < 16; ++c) qreg[c] = qs[h*16 + c];
        #pragma unroll
        for (int e = 0; e < 12; ++e) qpreg[e] = qps[h*12 + e];
        const float coef = coefS[h];
        const float* kb  = kT  + (size_t)(h*16)*NN + l;
        const float* kpb = kpT + (size_t)(h*12)*NN + l;
        const float* bgb = bG + (size_t)i*(Hn*NN) + (size_t)h*NN + l;
        float e[12];
        #pragma unroll
        for (int u = 0; u < 12; ++u) {
            const int jo = u * 64;
            float qk = 0.f;
            #pragma unroll
            for (int c = 0; c < 16; ++c) qk += qreg[c] * kb[(size_t)c*NN + jo];
            float d2s = 0.f;
            #pragma unroll
            for (int ee = 0; ee < 12; ++ee) {
                const float d = qpreg[ee] - kpb[(size_t)ee*NN + jo];
                d2s += d * d;
            }
            const float mterm = 100000.0f * (mi * mask[l + jo] - 1.0f);
            e[u] = 0.14433756729740643f*qk + bgb[jo] + coef*d2s + mterm;
        }
        float m = -1e30f;
        #pragma unroll
        for (int u = 0; u < 12; ++u) m = fmaxf(m, e[u]);
        #pragma unroll
        for (int off = 32; off > 0; off >>= 1) m = fmaxf(m, __shfl_xor(m, off));
        float ssum = 0.f;
        #pragma unroll
        for (int u = 0; u < 12; ++u) { e[u] = expf(e[u] - m); ssum += e[u]; }
        #pragma unroll
        for (int off = 32; off > 0; off >>= 1) ssum += __shfl_xor(ssum, off);
        const float inv = 1.0f / ssum;
        #pragma unroll
        for (int u = 0; u < 12; ++u) lg[h*LGS + l + u*64] = e[u] * inv;
    }
    __syncthreads();

    // ---- Phase 2 (r11 exact): o + o_pt, coalesced scalar src reads -------
    {
        float accA = 0.f;
        const float* srcA; int strA; int hA;
        if (t < 192) { srcA = v + t;          strA = 192; hA = t >> 4; }
        else         { srcA = vp + (t - 192); strA = 288; hA = (t - 192) / 24; }
        const float* arA = lg + hA * LGS;
        #pragma unroll 8
        for (int j = 0; j < NN; ++j) accA += arA[j] * srcA[(size_t)j * strA];

        float accB = 0.f;
        const int cB = 64 + t;                 // vp cols 64..287 (t<224)
        const float* srcB = vp + cB;
        const float* arB = lg + (cB / 24) * LGS;
        if (t < 224) {
            #pragma unroll 8
            for (int j = 0; j < NN; ++j) accB += arB[j] * srcB[(size_t)j * 288];
        }
        float* catr = cat + (size_t)i*CONCATn;
        if (t < 192) catr[t] = accA;
        else         pts[t - 192] = accA;
        if (t < 224) pts[64 + t] = accB;
    }
    __syncthreads();

    // ---- Phase 3 (r11 exact): frame invert + norms -----------------------
    if (t < 96) {
        const float gx = pts[t*3+0] - trans[i*3+0];
        const float gy = pts[t*3+1] - trans[i*3+1];
        const float gz = pts[t*3+2] - trans[i*3+2];
        const float lx = rot[i*9+0]*gx + rot[i*9+3]*gy + rot[i*9+6]*gz;
        const float ly = rot[i*9+1]*gx + rot[i*9+4]*gy + rot[i*9+7]*gz;
        const float lz = rot[i*9+2]*gx + rot[i*9+5]*gy + rot[i*9+8]*gz;
        float* catr = cat + (size_t)i*CONCATn;
        catr[192 + t] = lx;
        catr[288 + t] = ly;
        catr[384 + t] = lz;
        catr[480 + t] = sqrtf(lx*lx + ly*ly + lz*lz + 1e-8f);
    }

    // ---- Phase 4 (r13 variant): o_pair, float4 z + 2 j/instr + shfl ------
    {
        const int c4 = l & 31, jp = l >> 5;
        const float* zb = z + (size_t)i*NN*CZn + c4*4;
        const float* a0 = lg + (size_t)(3*w + 0)*LGS;
        const float* a1 = lg + (size_t)(3*w + 1)*LGS;
        const float* a2 = lg + (size_t)(3*w + 2)*LGS;
        float x00=0.f,x01=0.f,x02=0.f,x03=0.f;
        float x10=0.f,x11=0.f,x12=0.f,x13=0.f;
        float x20=0.f,x21=0.f,x22=0.f,x23=0.f;
        #pragma unroll 8
        for (int j2 = 0; j2 < 384; ++j2) {
            const int j = 2*j2 + jp;
            const float4 zv = *(const float4*)(zb + (size_t)j*CZn);
            const float A0 = a0[j], A1 = a1[j], A2 = a2[j];   // 2-way LDS broadcast
            x00 += A0*zv.x; x01 += A0*zv.y; x02 += A0*zv.z; x03 += A0*zv.w;
            x10 += A1*zv.x; x11 += A1*zv.y; x12 += A1*zv.z; x13 += A1*zv.w;
            x20 += A2*zv.x; x21 += A2*zv.y; x22 += A2*zv.z; x23 += A2*zv.w;
        }
        x00 += __shfl_xor(x00, 32); x01 += __shfl_xor(x01, 32);
        x02 += __shfl_xor(x02, 32); x03 += __shfl_xor(x03, 32);
        x10 += __shfl_xor(x10, 32); x11 += __shfl_xor(x11, 32);
        x12 += __shfl_xor(x12, 32); x13 += __shfl_xor(x13, 32);
        x20 += __shfl_xor(x20, 32); x21 += __shfl_xor(x21, 32);
        x22 += __shfl_xor(x22, 32); x23 += __shfl_xor(x23, 32);
        if (jp == 0) {
            float* cr = cat + (size_t)i*CONCATn + 576 + c4*4;
            float4 r0; r0.x=x00; r0.y=x01; r0.z=x02; r0.w=x03;
            float4 r1; r1.x=x10; r1.y=x11; r1.z=x12; r1.w=x13;
            float4 r2; r2.x=x20; r2.y=x21; r2.z=x22; r2.w=x23;
            *(float4*)(cr + (size_t)(3*w+0)*CZn) = r0;
            *(float4*)(cr + (size_t)(3*w+1)*CZn) = r1;
            *(float4*)(cr + (size_t)(3*w+2)*CZn) = r2;
        }
    }
}

// ---------------------------------------------------------------------------
// K5: out = cat @ Wout + bout.  Grid (192, 3), 128 thr.
// ---------------------------------------------------------------------------
__global__ __launch_bounds__(128) void out_kernel(
    const float* __restrict__ cat, const float* __restrict__ Wout,
    const float* __restrict__ bout, float* __restrict__ out)
{
    const int rt = blockIdx.x;
    const int ot = blockIdx.y;
    __shared__ float cl[4 * CONCATn];
    const int r0 = rt * 4;
    const float4* cb = (const float4*)(cat + (size_t)r0 * CONCATn);
    for (int idx = threadIdx.x; idx < CONCATn; idx += 128)
        ((float4*)cl)[idx] = cb[idx];
    __syncthreads();
    const int t = threadIdx.x;
    const int r  = t >> 5;
    const int o4 = t & 31;
    const int col = ot * 128 + o4 * 4;
    float4 acc; acc.x = 0.f; acc.y = 0.f; acc.z = 0.f; acc.w = 0.f;
    const float* wp = Wout + col;
    const float* cr = cl + r * CONCATn;
    #pragma unroll 8
    for (int kk = 0; kk < CONCATn; ++kk) {
        const float4 wv = *(const float4*)(wp + (size_t)kk * 384);
        const float cv = cr[kk];
        acc.x += cv * wv.x; acc.y += cv * wv.y;
        acc.z += cv * wv.z; acc.w += cv * wv.w;
    }
    const float4 bo = *(const float4*)(bout + col);
    acc.x += bo.x; acc.y += bo.y; acc.z += bo.z; acc.w += bo.w;
    *(float4*)(out + (size_t)(r0 + r) * 384 + col) = acc;
}

// ---------------------------------------------------------------------------
extern "C" void kernel_launch(void* const* d_in, const int* in_sizes, int n_in,
                              void* d_out, int out_size, void* d_ws, size_t ws_size,
                              hipStream_t stream)
{
    const float* s     = (const float*)d_in[0];
    const float* z     = (const float*)d_in[1];
    const float* rot   = (const float*)d_in[2];
    const float* trans = (const float*)d_in[3];
    const float* mask  = (const float*)d_in[4];
    const float* Wq    = (const float*)d_in[5];
    const float* bq    = (const float*)d_in[6];
    const float* Wkv   = (const float*)d_in[7];
    const float* bkv   = (const float*)d_in[8];
    const float* Wqp   = (const float*)d_in[9];
    const float* bqp   = (const float*)d_in[10];
    const float* Wkvp  = (const float*)d_in[11];
    const float* bkvp  = (const float*)d_in[12];
    const float* Wb    = (const float*)d_in[13];
    const float* bb    = (const float*)d_in[14];
    const float* head_w= (const float*)d_in[15];
    const float* Wout  = (const float*)d_in[16];
    const float* bout  = (const float*)d_in[17];
    float* out = (float*)d_out;

    float* ws    = (float*)d_ws;
    float* q     = ws;                  // 147456  [N][192]
    float* kT    = q     + 147456;      // 147456  [192][N]
    float* qp    = kT    + 147456;      // 110592  [N][144]
    float* kpT   = qp    + 110592;      // 110592  [144][N]
    float* v     = kpT   + 110592;      // 147456  [N][192]
    float* vp    = v     + 147456;      // 221184  [N][288]
    float* WbT   = vp    + 221184;      // 1536    [12][128]
    float* cat   = WbT   + 1536;        // 1622016
    float* bG    = cat   + 1622016;     // 7077888 (28 MB; overlaid with linG)
    float* linG  = bG;                  // dead before biasg runs

    hipLaunchKernelGGL(proj_gemm, dim3(48, 18), dim3(256), 0, stream,
        s, Wq, bq, Wkv, bkv, Wqp, bqp, Wkvp, bkvp, linG);
    hipLaunchKernelGGL(scatter_kernel, dim3(768), dim3(256), 0, stream,
        linG, rot, trans, Wb, q, kT, v, qp, kpT, vp, WbT);
    hipLaunchKernelGGL(biasg_kernel, dim3(12, 768), dim3(256), 0, stream,
        z, WbT, bb, bG);
    hipLaunchKernelGGL(mega_kernel, dim3(768), dim3(256), 0, stream,
        mask, q, qp, kT, kpT, bG, head_w, z, v, vp, rot, trans, cat);
    hipLaunchKernelGGL(out_kernel, dim3(192, 3), dim3(128), 0, stream,
        cat, Wout, bout, out);
}